// Round 2
// baseline (6649.042 us; speedup 1.0000x reference)
//
#include <hip/hip_runtime.h>
#include <hip/hip_bf16.h>

#define DEVINL __device__ __forceinline__

constexpr int B_   = 4;
constexpr int T_   = 2048;
constexpr int C_   = 1024;
constexpr int NTOK = B_ * T_;      // 8192
constexpr int HD   = 256;          // C_/4

typedef unsigned short u16;

DEVINL float bf2f(u16 u) {
    unsigned int x = ((unsigned int)u) << 16;
    return __uint_as_float(x);
}
DEVINL u16 f2bf(float f) {
    unsigned int x = __float_as_uint(f);
    unsigned int r = (x + 0x7fffu + ((x >> 16) & 1u)) >> 16;
    return (u16)r;
}
DEVINL float wave_reduce(float v) {
    #pragma unroll
    for (int off = 32; off > 0; off >>= 1) v += __shfl_down(v, off, 64);
    return v;
}

// ---------------------------------------------------------------------------
// dtype auto-detect: inspect even-indexed u16s of W_up. If the buffer holds
// bf16, every u16 is a genuine N(0,0.02) bf16 (exponent ~[113,124]).
// If it holds f32, even u16s are low mantissa halves -> exponent field
// uniform -> only ~15% land in a sane range. flag: 1 = bf16, 0 = f32.
// ---------------------------------------------------------------------------
__global__ __launch_bounds__(256) void detect_k(const u16* __restrict__ w,
                                                int* __restrict__ flag)
{
    int tid = threadIdx.x;
    int cnt = 0;
    for (int i = tid; i < 4096; i += 256) {
        u16 u = w[2 * i];
        int e = (u >> 7) & 0xFF;
        if (u == 0 || (e >= 96 && e <= 134)) cnt++;
    }
    __shared__ int sh[256];
    sh[tid] = cnt; __syncthreads();
    for (int s = 128; s > 0; s >>= 1) {
        if (tid < s) sh[tid] += sh[tid + s];
        __syncthreads();
    }
    if (tid == 0) *flag = (sh[0] > 2048) ? 1 : 0;
}

// flag-driven convert: src (bf16 or f32 per flag) -> f32 dst
__global__ __launch_bounds__(256) void conv_k(const void* __restrict__ src,
                                              float* __restrict__ dst, int n,
                                              const int* __restrict__ flag)
{
    int i = blockIdx.x * 256 + threadIdx.x;
    if (i >= n) return;
    if (*flag) dst[i] = bf2f(((const u16*)src)[i]);
    else       dst[i] = ((const float*)src)[i];
}

__global__ __launch_bounds__(256) void sumsq_k(const float* __restrict__ X,
                                               float* __restrict__ sumsq)
{
    int i = blockIdx.x * 256 + threadIdx.x;
    float f = X[i];
    float p = wave_reduce(f * f);
    __shared__ float r[4];
    int lane = threadIdx.x & 63, w = threadIdx.x >> 6;
    if (lane == 0) r[w] = p;
    __syncthreads();
    if (threadIdx.x == 0) atomicAdd(sumsq, r[0] + r[1] + r[2] + r[3]);
}

__global__ __launch_bounds__(256) void scale_k(float* __restrict__ X,
                                               const float* __restrict__ sumsq)
{
    int i = blockIdx.x * 256 + threadIdx.x;
    float F = sqrtf(*sumsq);
    float s = 16.0f / (1.1f * F);   // Gaussian: sigma_max ~= F/16; 10% margin
    X[i] *= s;
}

// ---------------------------------------------------------------------------
// f32 tiled GEMM family: BM=BN=64, BK=16, 256 threads, 4x4 microtile.
// All dims are multiples of tile sizes -> no bounds checks.
// ---------------------------------------------------------------------------

// C[m,n] = beta * sum_k A[m,k]*B[k,n]  + alpha*D[m,n] (D may be null)
__global__ __launch_bounds__(256) void gemm_ab_f32(
    const float* __restrict__ A, const float* __restrict__ Bm,
    const float* __restrict__ D, float* __restrict__ C,
    int M, int N, int K, float alpha, float beta)
{
    __shared__ float As[16][68];
    __shared__ float Bs[16][68];
    const int bm = blockIdx.y * 64, bn = blockIdx.x * 64;
    const int tid = threadIdx.x;
    const int tx = tid & 15, ty = tid >> 4;
    const int am = tid >> 2, akq = (tid & 3) << 2;     // A tile: 64 m x 16 k
    const int bk = tid >> 4, bnq = (tid & 15) << 2;    // B tile: 16 k x 64 n
    float acc[4][4] = {};
    for (int k0 = 0; k0 < K; k0 += 16) {
        float4 av = *(const float4*)(A + (size_t)(bm + am) * K + k0 + akq);
        As[akq + 0][am] = av.x; As[akq + 1][am] = av.y;
        As[akq + 2][am] = av.z; As[akq + 3][am] = av.w;
        *(float4*)&Bs[bk][bnq] = *(const float4*)(Bm + (size_t)(k0 + bk) * N + bn + bnq);
        __syncthreads();
        #pragma unroll
        for (int k = 0; k < 16; ++k) {
            float a4[4], b4[4];
            *(float4*)a4 = *(const float4*)&As[k][ty << 2];
            *(float4*)b4 = *(const float4*)&Bs[k][tx << 2];
            #pragma unroll
            for (int i = 0; i < 4; ++i)
                #pragma unroll
                for (int j = 0; j < 4; ++j) acc[i][j] += a4[i] * b4[j];
        }
        __syncthreads();
    }
    #pragma unroll
    for (int i = 0; i < 4; ++i) {
        size_t row = (size_t)(bm + (ty << 2) + i);
        #pragma unroll
        for (int j = 0; j < 4; ++j) {
            size_t idx = row * N + bn + (tx << 2) + j;
            float v = beta * acc[i][j];
            if (D) v += alpha * D[idx];
            C[idx] = v;
        }
    }
}

// C[i,j] = sum_k A[k,i]*B[k,j]   (A: KxM, B: KxN row-major) — for X^T X
__global__ __launch_bounds__(256) void gemm_atb_f32(
    const float* __restrict__ A, const float* __restrict__ Bm,
    float* __restrict__ C, int M, int N, int K)
{
    __shared__ float As[16][68];
    __shared__ float Bs[16][68];
    const int bm = blockIdx.y * 64, bn = blockIdx.x * 64;
    const int tid = threadIdx.x;
    const int tx = tid & 15, ty = tid >> 4;
    const int bk = tid >> 4, bq = (tid & 15) << 2;   // both tiles: 16 k x 64 cols
    float acc[4][4] = {};
    for (int k0 = 0; k0 < K; k0 += 16) {
        *(float4*)&As[bk][bq] = *(const float4*)(A + (size_t)(k0 + bk) * M + bm + bq);
        *(float4*)&Bs[bk][bq] = *(const float4*)(Bm + (size_t)(k0 + bk) * N + bn + bq);
        __syncthreads();
        #pragma unroll
        for (int k = 0; k < 16; ++k) {
            float a4[4], b4[4];
            *(float4*)a4 = *(const float4*)&As[k][ty << 2];
            *(float4*)b4 = *(const float4*)&Bs[k][tx << 2];
            #pragma unroll
            for (int i = 0; i < 4; ++i)
                #pragma unroll
                for (int j = 0; j < 4; ++j) acc[i][j] += a4[i] * b4[j];
        }
        __syncthreads();
    }
    #pragma unroll
    for (int i = 0; i < 4; ++i) {
        size_t row = (size_t)(bm + (ty << 2) + i);
        #pragma unroll
        for (int j = 0; j < 4; ++j)
            C[row * N + bn + (tx << 2) + j] = acc[i][j];
    }
}

// C[m,n] = sum_k A[m,k]*B[n,k]   (both f32 row-major, k-contiguous)
__global__ __launch_bounds__(256) void gemm_abt_f32(
    const float* __restrict__ A, const float* __restrict__ Bm,
    float* __restrict__ C, int M, int N, int K)
{
    __shared__ float As[16][68];
    __shared__ float Bs[16][68];
    const int bm = blockIdx.y * 64, bn = blockIdx.x * 64;
    const int tid = threadIdx.x;
    const int tx = tid & 15, ty = tid >> 4;
    const int am = tid >> 2, akq = (tid & 3) << 2;   // 64 rows x 16 k (A and B)
    float acc[4][4] = {};
    for (int k0 = 0; k0 < K; k0 += 16) {
        float4 av = *(const float4*)(A + (size_t)(bm + am) * K + k0 + akq);
        As[akq + 0][am] = av.x; As[akq + 1][am] = av.y;
        As[akq + 2][am] = av.z; As[akq + 3][am] = av.w;
        float4 bv = *(const float4*)(Bm + (size_t)(bn + am) * K + k0 + akq);
        Bs[akq + 0][am] = bv.x; Bs[akq + 1][am] = bv.y;
        Bs[akq + 2][am] = bv.z; Bs[akq + 3][am] = bv.w;
        __syncthreads();
        #pragma unroll
        for (int k = 0; k < 16; ++k) {
            float a4[4], b4[4];
            *(float4*)a4 = *(const float4*)&As[k][ty << 2];
            *(float4*)b4 = *(const float4*)&Bs[k][tx << 2];
            #pragma unroll
            for (int i = 0; i < 4; ++i)
                #pragma unroll
                for (int j = 0; j < 4; ++j) acc[i][j] += a4[i] * b4[j];
        }
        __syncthreads();
    }
    #pragma unroll
    for (int i = 0; i < 4; ++i) {
        size_t row = (size_t)(bm + (ty << 2) + i);
        #pragma unroll
        for (int j = 0; j < 4; ++j)
            C[row * N + bn + (tx << 2) + j] = acc[i][j];
    }
}

// out[m,n] = cast( sum_k (Q[m,k]*V[m,k]) * W[n,k] )  — flag-driven store
__global__ __launch_bounds__(256) void gemm_prod_abt_f32(
    const float* __restrict__ Q, const float* __restrict__ V,
    const float* __restrict__ Wf, void* __restrict__ out,
    int M, int N, int K, const int* __restrict__ flag)
{
    __shared__ float As[16][68];
    __shared__ float Bs[16][68];
    const int bm = blockIdx.y * 64, bn = blockIdx.x * 64;
    const int tid = threadIdx.x;
    const int tx = tid & 15, ty = tid >> 4;
    const int am = tid >> 2, akq = (tid & 3) << 2;
    float acc[4][4] = {};
    for (int k0 = 0; k0 < K; k0 += 16) {
        size_t aoff = (size_t)(bm + am) * K + k0 + akq;
        float4 qv = *(const float4*)(Q + aoff);
        float4 vv = *(const float4*)(V + aoff);
        As[akq + 0][am] = qv.x * vv.x; As[akq + 1][am] = qv.y * vv.y;
        As[akq + 2][am] = qv.z * vv.z; As[akq + 3][am] = qv.w * vv.w;
        float4 bv = *(const float4*)(Wf + (size_t)(bn + am) * K + k0 + akq);
        Bs[akq + 0][am] = bv.x; Bs[akq + 1][am] = bv.y;
        Bs[akq + 2][am] = bv.z; Bs[akq + 3][am] = bv.w;
        __syncthreads();
        #pragma unroll
        for (int k = 0; k < 16; ++k) {
            float a4[4], b4[4];
            *(float4*)a4 = *(const float4*)&As[k][ty << 2];
            *(float4*)b4 = *(const float4*)&Bs[k][tx << 2];
            #pragma unroll
            for (int i = 0; i < 4; ++i)
                #pragma unroll
                for (int j = 0; j < 4; ++j) acc[i][j] += a4[i] * b4[j];
        }
        __syncthreads();
    }
    const int bf = *flag;
    #pragma unroll
    for (int i = 0; i < 4; ++i) {
        size_t row = (size_t)(bm + (ty << 2) + i);
        #pragma unroll
        for (int j = 0; j < 4; ++j) {
            size_t idx = row * N + bn + (tx << 2) + j;
            if (bf) ((u16*)out)[idx] = f2bf(acc[i][j]);
            else    ((float*)out)[idx] = acc[i][j];
        }
    }
}

// flag-driven store of f32 src into d_out at element offset
__global__ __launch_bounds__(256) void store_k(const float* __restrict__ src,
                                               void* __restrict__ out, int n,
                                               size_t elemoff,
                                               const int* __restrict__ flag)
{
    int i = blockIdx.x * 256 + threadIdx.x;
    if (i >= n) return;
    if (*flag) ((u16*)out)[elemoff + i] = f2bf(src[i]);
    else       ((float*)out)[elemoff + i] = src[i];
}

// idW[j] = sum_i identf[i] * W[i,j]
__global__ __launch_bounds__(256) void idw_k(
    const float* __restrict__ identf, const float* __restrict__ W,
    float* __restrict__ idW)
{
    int jj = blockIdx.x * 256 + threadIdx.x;   // 0..1023
    float acc = 0.0f;
    for (int i = 0; i < C_; ++i) acc += identf[i] * W[(size_t)i * C_ + jj];
    idW[jj] = acc;
}

// ---------------------------------------------------------------------------
// scan combine: one block (256 threads) per token. thread j owns dim j of
// each of the 4 lanes. new = left + rmsnorm(att@v)/denom
// ---------------------------------------------------------------------------
__global__ __launch_bounds__(256) void combine_k(
    const float* __restrict__ cur, const float* __restrict__ xW,
    const float* __restrict__ idW, const float* __restrict__ identf,
    float* __restrict__ nxt, int d)
{
    const int token = blockIdx.x;
    const int t = token & (T_ - 1);
    const int j = threadIdx.x;
    const bool hl = (t >= d);
    const float* leftp  = hl ? cur + (size_t)(token - d) * C_ : identf;
    const float* leftW  = hl ? xW  + (size_t)(token - d) * C_ : idW;
    const float* rightp = cur + (size_t)token * C_;
    const float* rightW = xW  + (size_t)token * C_;

    float q[4], k[4], v[4];
    #pragma unroll
    for (int l = 0; l < 4; ++l) {
        q[l] = leftp[l * HD + j];
        k[l] = rightp[l * HD + j];
        v[l] = leftW[l * HD + j] + rightW[l * HD + j];
    }

    __shared__ float red[4][16];
    __shared__ float att[16];
    const int lane = j & 63, wid = j >> 6;

    // scores[l][m] = (q_l . k_m) / 16
    #pragma unroll
    for (int l = 0; l < 4; ++l)
        #pragma unroll
        for (int m = 0; m < 4; ++m) {
            float p = wave_reduce(q[l] * k[m]);
            if (lane == 0) red[wid][l * 4 + m] = p;
        }
    __syncthreads();
    if (j < 16) red[0][j] = (red[0][j] + red[1][j] + red[2][j] + red[3][j]) * 0.0625f;
    __syncthreads();
    if (j < 4) {
        float s0 = red[0][j * 4 + 0], s1 = red[0][j * 4 + 1];
        float s2 = red[0][j * 4 + 2], s3 = red[0][j * 4 + 3];
        float mx = fmaxf(fmaxf(s0, s1), fmaxf(s2, s3));
        float e0 = __expf(s0 - mx), e1 = __expf(s1 - mx);
        float e2 = __expf(s2 - mx), e3 = __expf(s3 - mx);
        float inv = 1.0f / (e0 + e1 + e2 + e3);
        att[j * 4 + 0] = e0 * inv; att[j * 4 + 1] = e1 * inv;
        att[j * 4 + 2] = e2 * inv; att[j * 4 + 3] = e3 * inv;
    }
    __syncthreads();

    float z[4];
    #pragma unroll
    for (int l = 0; l < 4; ++l)
        z[l] = att[l * 4 + 0] * v[0] + att[l * 4 + 1] * v[1]
             + att[l * 4 + 2] * v[2] + att[l * 4 + 3] * v[3];

    // rms per lane
    #pragma unroll
    for (int l = 0; l < 4; ++l) {
        float p = wave_reduce(z[l] * z[l]);
        if (lane == 0) red[wid][l] = p;
    }
    __syncthreads();
    if (j < 4) {
        float ss = red[0][j] + red[1][j] + red[2][j] + red[3][j];
        att[j] = rsqrtf(ss * (1.0f / HD) + 1e-8f);   // reuse att[0..3] as r_l
    }
    __syncthreads();

    #pragma unroll
    for (int l = 0; l < 4; ++l) {
        float zn = z[l] * att[l] * (1.0f / (float)(l + 1));
        nxt[(size_t)token * C_ + l * HD + j] = q[l] + zn;
    }
}

// ---------------------------------------------------------------------------
extern "C" void kernel_launch(void* const* d_in, const int* in_sizes, int n_in,
                              void* d_out, int out_size, void* d_ws, size_t ws_size,
                              hipStream_t stream)
{
    const void* x     = d_in[0];
    const void* Wup   = d_in[1];
    const void* Wv    = d_in[2];
    const void* Wproj = d_in[3];
    const void* ident = d_in[4];
    const void* Wraw  = d_in[5];

    float* ws = (float*)d_ws;
    int*   flagp  = (int*)ws;                    // meta[0]
    float* sumsqp = ws + 1;                      // meta[1]
    float* W0     = ws + 256;                    // 1M
    float* W1     = W0 + (1 << 20);              // 1M
    float* G      = W1 + (1 << 20);              // 1M (also reused for W_up/W_v/W_proj f32)
    float* identf = G + (1 << 20);               // 1024
    float* idW    = identf + 1024;               // 1024
    float* stA    = idW + 1024;                  // 8M
    float* stB    = stA + (size_t)NTOK * C_;     // 8M
    float* xWb    = stB + (size_t)NTOK * C_;     // 8M

    const int NC = C_ * C_;          // 1M
    const int NX = NTOK * C_;        // 8M

    // ---- dtype detection ----
    detect_k<<<1, 256, 0, stream>>>((const u16*)Wup, flagp);

    // ---- polar(W_raw) via Newton-Schulz ----
    hipMemsetAsync(sumsqp, 0, sizeof(float), stream);
    conv_k<<<NC / 256, 256, 0, stream>>>(Wraw, W0, NC, flagp);
    sumsq_k<<<NC / 256, 256, 0, stream>>>(W0, sumsqp);
    scale_k<<<NC / 256, 256, 0, stream>>>(W0, sumsqp);

    float* X = W0; float* Y = W1;
    const dim3 gNS(16, 16);
    for (int it = 0; it < 23; ++it) {
        bool polish = (it >= 18);
        float a = polish ? 1.5f : 2.0f;
        float b = polish ? -0.5f : -1.0f;
        gemm_atb_f32<<<gNS, 256, 0, stream>>>(X, X, G, C_, C_, C_);
        gemm_ab_f32<<<gNS, 256, 0, stream>>>(X, G, X, Y, C_, C_, C_, a, b);
        float* tmp = X; X = Y; Y = tmp;
    }
    // X now holds W = polar(W_raw); G and (the other of W0/W1) are free.

    conv_k<<<4, 256, 0, stream>>>(ident, identf, 1024, flagp);
    idw_k<<<4, 256, 0, stream>>>(identf, X, idW);

    // ---- q0 = x @ Wup^T ----   (x_f32 staged in stB, Wup_f32 in G)
    const dim3 gBig(16, 128);
    conv_k<<<NX / 256, 256, 0, stream>>>(x, stB, NX, flagp);
    conv_k<<<NC / 256, 256, 0, stream>>>(Wup, G, NC, flagp);
    gemm_abt_f32<<<gBig, 256, 0, stream>>>(stB, G, stA, NTOK, C_, C_);

    // ---- scan: 11 Hillis-Steele steps ----
    float* cur = stA; float* nxt = stB;
    for (int d = 1; d < T_; d <<= 1) {
        gemm_ab_f32<<<gBig, 256, 0, stream>>>(cur, X, nullptr, xWb, NTOK, C_, C_, 0.0f, 1.0f);
        combine_k<<<NTOK, 256, 0, stream>>>(cur, xWb, idW, identf, nxt, d);
        float* tmp = cur; cur = nxt; nxt = tmp;
    }
    // 11 steps (odd) -> cur == stB holds q; stA and xWb free.

    // ---- v = x @ Wv^T ----  (x_f32 re-staged in xWb, Wv_f32 in G, v -> stA)
    conv_k<<<NX / 256, 256, 0, stream>>>(x, xWb, NX, flagp);
    conv_k<<<NC / 256, 256, 0, stream>>>(Wv, G, NC, flagp);
    gemm_abt_f32<<<gBig, 256, 0, stream>>>(xWb, G, stA, NTOK, C_, C_);

    // ---- Y = (q * v) @ Wproj^T -> d_out[0 : NX] ----
    conv_k<<<NC / 256, 256, 0, stream>>>(Wproj, G, NC, flagp);
    gemm_prod_abt_f32<<<gBig, 256, 0, stream>>>(cur, stA, G, d_out, NTOK, C_, C_, flagp);

    // ---- second output: q ----
    store_k<<<NX / 256, 256, 0, stream>>>(cur, d_out, NX, (size_t)NX, flagp);
}

// Round 6
// 6094.233 us; speedup vs baseline: 1.0910x; 1.0910x over previous
//
#include <hip/hip_runtime.h>
#include <hip/hip_bf16.h>

#define DEVINL __device__ __forceinline__

constexpr int B_   = 4;
constexpr int T_   = 2048;
constexpr int C_   = 1024;
constexpr int NTOK = B_ * T_;      // 8192
constexpr int HD   = 256;          // C_/4

typedef unsigned short u16;
typedef __attribute__((ext_vector_type(8))) short  frag_ab;  // 8 bf16 (4 VGPRs)
typedef __attribute__((ext_vector_type(4))) float  frag_cd;  // 4 fp32
typedef __attribute__((ext_vector_type(8))) u16    u16x8;

DEVINL float bf2f(u16 u) {
    unsigned int x = ((unsigned int)u) << 16;
    return __uint_as_float(x);
}
DEVINL u16 f2bf(float f) {
    unsigned int x = __float_as_uint(f);
    unsigned int r = (x + 0x7fffu + ((x >> 16) & 1u)) >> 16;
    return (u16)r;
}
DEVINL float wave_reduce(float v) {
    #pragma unroll
    for (int off = 32; off > 0; off >>= 1) v += __shfl_down(v, off, 64);
    return v;
}
DEVINL void gl_lds16(const void* g, void* l) {
    __builtin_amdgcn_global_load_lds(
        (const __attribute__((address_space(1))) unsigned int*)g,
        (__attribute__((address_space(3))) unsigned int*)l, 16, 0, 0);
}

// ---------------------------------------------------------------------------
// dtype auto-detect (flag: 1 = bf16 inputs, 0 = f32 inputs)
// ---------------------------------------------------------------------------
__global__ __launch_bounds__(256) void detect_k(const u16* __restrict__ w,
                                                int* __restrict__ flag)
{
    int tid = threadIdx.x;
    int cnt = 0;
    for (int i = tid; i < 4096; i += 256) {
        u16 u = w[2 * i];
        int e = (u >> 7) & 0xFF;
        if (u == 0 || (e >= 96 && e <= 134)) cnt++;
    }
    __shared__ int sh[256];
    sh[tid] = cnt; __syncthreads();
    for (int s = 128; s > 0; s >>= 1) {
        if (tid < s) sh[tid] += sh[tid + s];
        __syncthreads();
    }
    if (tid == 0) *flag = (sh[0] > 2048) ? 1 : 0;
}

__global__ __launch_bounds__(256) void conv_k(const void* __restrict__ src,
                                              float* __restrict__ dst, int n,
                                              const int* __restrict__ flag)
{
    int i = blockIdx.x * 256 + threadIdx.x;
    if (i >= n) return;
    if (*flag) dst[i] = bf2f(((const u16*)src)[i]);
    else       dst[i] = ((const float*)src)[i];
}

__global__ __launch_bounds__(256) void sumsq_k(const float* __restrict__ X,
                                               float* __restrict__ sumsq)
{
    int i = blockIdx.x * 256 + threadIdx.x;
    float f = X[i];
    float p = wave_reduce(f * f);
    __shared__ float r[4];
    int lane = threadIdx.x & 63, w = threadIdx.x >> 6;
    if (lane == 0) r[w] = p;
    __syncthreads();
    if (threadIdx.x == 0) atomicAdd(sumsq, r[0] + r[1] + r[2] + r[3]);
}

__global__ __launch_bounds__(256) void scale_k(float* __restrict__ X,
                                               const float* __restrict__ sumsq)
{
    int i = blockIdx.x * 256 + threadIdx.x;
    float F = sqrtf(*sumsq);
    float s = 16.0f / (1.1f * F);   // Gaussian: sigma_max ~= F/16; 10% margin
    X[i] *= s;
}

// ---------------------------------------------------------------------------
// f32 tiled GEMMs — EXACT round-2 kernels (bit-proven q path + NS)
// ---------------------------------------------------------------------------
__global__ __launch_bounds__(256) void gemm_ab_f32(
    const float* __restrict__ A, const float* __restrict__ Bm,
    const float* __restrict__ D, float* __restrict__ C,
    int M, int N, int K, float alpha, float beta)
{
    __shared__ float As[16][68];
    __shared__ float Bs[16][68];
    const int bm = blockIdx.y * 64, bn = blockIdx.x * 64;
    const int tid = threadIdx.x;
    const int tx = tid & 15, ty = tid >> 4;
    const int am = tid >> 2, akq = (tid & 3) << 2;
    const int bk = tid >> 4, bnq = (tid & 15) << 2;
    float acc[4][4] = {};
    for (int k0 = 0; k0 < K; k0 += 16) {
        float4 av = *(const float4*)(A + (size_t)(bm + am) * K + k0 + akq);
        As[akq + 0][am] = av.x; As[akq + 1][am] = av.y;
        As[akq + 2][am] = av.z; As[akq + 3][am] = av.w;
        *(float4*)&Bs[bk][bnq] = *(const float4*)(Bm + (size_t)(k0 + bk) * N + bn + bnq);
        __syncthreads();
        #pragma unroll
        for (int k = 0; k < 16; ++k) {
            float a4[4], b4[4];
            *(float4*)a4 = *(const float4*)&As[k][ty << 2];
            *(float4*)b4 = *(const float4*)&Bs[k][tx << 2];
            #pragma unroll
            for (int i = 0; i < 4; ++i)
                #pragma unroll
                for (int j = 0; j < 4; ++j) acc[i][j] += a4[i] * b4[j];
        }
        __syncthreads();
    }
    #pragma unroll
    for (int i = 0; i < 4; ++i) {
        size_t row = (size_t)(bm + (ty << 2) + i);
        #pragma unroll
        for (int j = 0; j < 4; ++j) {
            size_t idx = row * N + bn + (tx << 2) + j;
            float v = beta * acc[i][j];
            if (D) v += alpha * D[idx];
            C[idx] = v;
        }
    }
}

__global__ __launch_bounds__(256) void gemm_atb_f32(
    const float* __restrict__ A, const float* __restrict__ Bm,
    float* __restrict__ C, int M, int N, int K)
{
    __shared__ float As[16][68];
    __shared__ float Bs[16][68];
    const int bm = blockIdx.y * 64, bn = blockIdx.x * 64;
    const int tid = threadIdx.x;
    const int tx = tid & 15, ty = tid >> 4;
    const int bk = tid >> 4, bq = (tid & 15) << 2;
    float acc[4][4] = {};
    for (int k0 = 0; k0 < K; k0 += 16) {
        *(float4*)&As[bk][bq] = *(const float4*)(A + (size_t)(k0 + bk) * M + bm + bq);
        *(float4*)&Bs[bk][bq] = *(const float4*)(Bm + (size_t)(k0 + bk) * N + bn + bq);
        __syncthreads();
        #pragma unroll
        for (int k = 0; k < 16; ++k) {
            float a4[4], b4[4];
            *(float4*)a4 = *(const float4*)&As[k][ty << 2];
            *(float4*)b4 = *(const float4*)&Bs[k][tx << 2];
            #pragma unroll
            for (int i = 0; i < 4; ++i)
                #pragma unroll
                for (int j = 0; j < 4; ++j) acc[i][j] += a4[i] * b4[j];
        }
        __syncthreads();
    }
    #pragma unroll
    for (int i = 0; i < 4; ++i) {
        size_t row = (size_t)(bm + (ty << 2) + i);
        #pragma unroll
        for (int j = 0; j < 4; ++j)
            C[row * N + bn + (tx << 2) + j] = acc[i][j];
    }
}

// C[m,n] = sum_k A[m,k]*B[n,k]  (q0 path — exact round-2 kernel)
__global__ __launch_bounds__(256) void gemm_abt_f32(
    const float* __restrict__ A, const float* __restrict__ Bm,
    float* __restrict__ C, int M, int N, int K)
{
    __shared__ float As[16][68];
    __shared__ float Bs[16][68];
    const int bm = blockIdx.y * 64, bn = blockIdx.x * 64;
    const int tid = threadIdx.x;
    const int tx = tid & 15, ty = tid >> 4;
    const int am = tid >> 2, akq = (tid & 3) << 2;
    float acc[4][4] = {};
    for (int k0 = 0; k0 < K; k0 += 16) {
        float4 av = *(const float4*)(A + (size_t)(bm + am) * K + k0 + akq);
        As[akq + 0][am] = av.x; As[akq + 1][am] = av.y;
        As[akq + 2][am] = av.z; As[akq + 3][am] = av.w;
        float4 bv = *(const float4*)(Bm + (size_t)(bn + am) * K + k0 + akq);
        Bs[akq + 0][am] = bv.x; Bs[akq + 1][am] = bv.y;
        Bs[akq + 2][am] = bv.z; Bs[akq + 3][am] = bv.w;
        __syncthreads();
        #pragma unroll
        for (int k = 0; k < 16; ++k) {
            float a4[4], b4[4];
            *(float4*)a4 = *(const float4*)&As[k][ty << 2];
            *(float4*)b4 = *(const float4*)&Bs[k][tx << 2];
            #pragma unroll
            for (int i = 0; i < 4; ++i)
                #pragma unroll
                for (int j = 0; j < 4; ++j) acc[i][j] += a4[i] * b4[j];
        }
        __syncthreads();
    }
    #pragma unroll
    for (int i = 0; i < 4; ++i) {
        size_t row = (size_t)(bm + (ty << 2) + i);
        #pragma unroll
        for (int j = 0; j < 4; ++j)
            C[row * N + bn + (tx << 2) + j] = acc[i][j];
    }
}

// ---------------------------------------------------------------------------
// Fast f32 GEMM for the scan: C[m,n] = sum_k A[m,k]*B[k,n].
// 128x128 tile, BK=16, 256 threads, 8x8 microtile.
// BIT-EXACT vs gemm_ab_f32(beta=1): each output element is one fmac chain
// over strictly ascending k (same contraction, same order) — only the tile
// shape and staging differ, which cannot change f32 results.
// ---------------------------------------------------------------------------
__global__ __launch_bounds__(256) void gemm_ab_f32_big(
    const float* __restrict__ A, const float* __restrict__ Bm,
    float* __restrict__ C, int M, int N, int K)
{
    __shared__ float As[16][128];   // As[k][m]
    __shared__ float Bs[16][128];   // Bs[k][n]
    const int bm = blockIdx.y * 128, bn = blockIdx.x * 128;
    const int tid = threadIdx.x;
    const int tx = tid & 15, ty = tid >> 4;          // 16 x 16 threads
    const int am = tid >> 1, ak = (tid & 1) * 8;     // A stage: 128 m x 16 k
    const int bk = tid >> 4, bno = (tid & 15) * 8;   // B stage: 16 k x 128 n

    float acc[8][8] = {};
    for (int k0 = 0; k0 < K; k0 += 16) {
        float4 a0 = *(const float4*)(A + (size_t)(bm + am) * K + k0 + ak);
        float4 a1 = *(const float4*)(A + (size_t)(bm + am) * K + k0 + ak + 4);
        As[ak + 0][am] = a0.x; As[ak + 1][am] = a0.y;
        As[ak + 2][am] = a0.z; As[ak + 3][am] = a0.w;
        As[ak + 4][am] = a1.x; As[ak + 5][am] = a1.y;
        As[ak + 6][am] = a1.z; As[ak + 7][am] = a1.w;
        *(float4*)&Bs[bk][bno]     = *(const float4*)(Bm + (size_t)(k0 + bk) * N + bn + bno);
        *(float4*)&Bs[bk][bno + 4] = *(const float4*)(Bm + (size_t)(k0 + bk) * N + bn + bno + 4);
        __syncthreads();
        #pragma unroll
        for (int k = 0; k < 16; ++k) {
            float a8[8], b8[8];
            *(float4*)&a8[0] = *(const float4*)&As[k][ty * 8];
            *(float4*)&a8[4] = *(const float4*)&As[k][ty * 8 + 4];
            *(float4*)&b8[0] = *(const float4*)&Bs[k][tx * 8];
            *(float4*)&b8[4] = *(const float4*)&Bs[k][tx * 8 + 4];
            #pragma unroll
            for (int i = 0; i < 8; ++i)
                #pragma unroll
                for (int j = 0; j < 8; ++j) acc[i][j] += a8[i] * b8[j];
        }
        __syncthreads();
    }
    #pragma unroll
    for (int i = 0; i < 8; ++i) {
        size_t row = (size_t)(bm + ty * 8 + i);
        float* cp = C + row * N + bn + tx * 8;
        *(float4*)(cp)     = *(float4*)&acc[i][0];
        *(float4*)(cp + 4) = *(float4*)&acc[i][4];
    }
}

// ---------------------------------------------------------------------------
// MFMA bf16 GEMM (plain): C[m,n] = sum_k A[m,k] * B[n,k]
// Output-0 path only (v, final projection) — proven in rounds 3/4/5.
// ---------------------------------------------------------------------------
__global__ __launch_bounds__(256) void gemm_mfma(
    const void* __restrict__ Asrc, const float* __restrict__ Vf, int amode,
    const void* __restrict__ Bsrc, int bmode,
    void* __restrict__ Cdst, int cmode,
    const int* __restrict__ flag, int M, int N, int K)
{
    __shared__ u16 As[128 * 32];
    __shared__ u16 Bs[128 * 32];
    const int fl  = *flag;
    const int abf = (amode == 2) ? fl : amode;
    const int bbf = (bmode == 2) ? fl : bmode;
    const int cbf = (cmode == 1) ? fl : 0;

    const int bm = blockIdx.y * 128, bn = blockIdx.x * 128;
    const int tid = threadIdx.x;
    const int l = tid & 63, w = tid >> 6;
    const int mbase = (w & 1) * 64, nbase = (w >> 1) * 64;
    const int lrow = l & 15;
    const int kq = (l >> 4) << 3;

    const u16*   Ab = (const u16*)Asrc;
    const float* Af = (const float*)Asrc;
    const u16*   Bb = (const u16*)Bsrc;
    const float* Bf = (const float*)Bsrc;

    frag_cd acc[4][4];
    #pragma unroll
    for (int i = 0; i < 4; ++i)
        #pragma unroll
        for (int j = 0; j < 4; ++j)
            #pragma unroll
            for (int r = 0; r < 4; ++r) acc[i][j][r] = 0.0f;

    for (int k0 = 0; k0 < K; k0 += 32) {
        #pragma unroll
        for (int half = 0; half < 2; ++half) {
            const int c   = tid + half * 256;
            const int row = c >> 2;
            const int ko  = (c & 3) << 3;
            u16* lA = &As[c << 3];
            if (abf) {
                gl_lds16(Ab + (size_t)(bm + row) * K + k0 + ko, lA);
            } else {
                const float* src = Af + (size_t)(bm + row) * K + k0 + ko;
                float4 f0 = *(const float4*)(src);
                float4 f1 = *(const float4*)(src + 4);
                if (Vf) {
                    const float* vs = Vf + (size_t)(bm + row) * K + k0 + ko;
                    float4 v0 = *(const float4*)(vs);
                    float4 v1 = *(const float4*)(vs + 4);
                    f0.x *= v0.x; f0.y *= v0.y; f0.z *= v0.z; f0.w *= v0.w;
                    f1.x *= v1.x; f1.y *= v1.y; f1.z *= v1.z; f1.w *= v1.w;
                }
                u16x8 p;
                p[0] = f2bf(f0.x); p[1] = f2bf(f0.y); p[2] = f2bf(f0.z); p[3] = f2bf(f0.w);
                p[4] = f2bf(f1.x); p[5] = f2bf(f1.y); p[6] = f2bf(f1.z); p[7] = f2bf(f1.w);
                *(u16x8*)lA = p;
            }
            u16* lB = &Bs[c << 3];
            if (bbf) {
                gl_lds16(Bb + (size_t)(bn + row) * K + k0 + ko, lB);
            } else {
                const float* src = Bf + (size_t)(bn + row) * K + k0 + ko;
                float4 f0 = *(const float4*)(src);
                float4 f1 = *(const float4*)(src + 4);
                u16x8 p;
                p[0] = f2bf(f0.x); p[1] = f2bf(f0.y); p[2] = f2bf(f0.z); p[3] = f2bf(f0.w);
                p[4] = f2bf(f1.x); p[5] = f2bf(f1.y); p[6] = f2bf(f1.z); p[7] = f2bf(f1.w);
                *(u16x8*)lB = p;
            }
        }
        __syncthreads();

        frag_ab a[4], b[4];
        #pragma unroll
        for (int i = 0; i < 4; ++i)
            a[i] = *(const frag_ab*)&As[(mbase + 16 * i + lrow) * 32 + kq];
        #pragma unroll
        for (int j = 0; j < 4; ++j)
            b[j] = *(const frag_ab*)&Bs[(nbase + 16 * j + lrow) * 32 + kq];
        #pragma unroll
        for (int i = 0; i < 4; ++i)
            #pragma unroll
            for (int j = 0; j < 4; ++j)
                acc[i][j] = __builtin_amdgcn_mfma_f32_16x16x32_bf16(
                    a[i], b[j], acc[i][j], 0, 0, 0);
        __syncthreads();
    }

    const int quad = l >> 4;
    #pragma unroll
    for (int i = 0; i < 4; ++i) {
        #pragma unroll
        for (int j = 0; j < 4; ++j) {
            const int coln = bn + nbase + 16 * j + lrow;
            #pragma unroll
            for (int r = 0; r < 4; ++r) {
                const int rowm = bm + mbase + 16 * i + quad * 4 + r;
                const size_t idx = (size_t)rowm * N + coln;
                float v = acc[i][j][r];
                if (cbf) ((u16*)Cdst)[idx] = f2bf(v);
                else     ((float*)Cdst)[idx] = v;
            }
        }
    }
}

// flag-driven store of f32 src into d_out at element offset
__global__ __launch_bounds__(256) void store_k(const float* __restrict__ src,
                                               void* __restrict__ out, int n,
                                               size_t elemoff,
                                               const int* __restrict__ flag)
{
    int i = blockIdx.x * 256 + threadIdx.x;
    if (i >= n) return;
    if (*flag) ((u16*)out)[elemoff + i] = f2bf(src[i]);
    else       ((float*)out)[elemoff + i] = src[i];
}

// idW[j] = sum_i identf[i] * W[i,j]
__global__ __launch_bounds__(256) void idw_k(
    const float* __restrict__ identf, const float* __restrict__ W,
    float* __restrict__ idW)
{
    int jj = blockIdx.x * 256 + threadIdx.x;   // 0..1023
    float acc = 0.0f;
    for (int i = 0; i < C_; ++i) acc += identf[i] * W[(size_t)i * C_ + jj];
    idW[jj] = acc;
}

// ---------------------------------------------------------------------------
// scan combine: one block (256 threads) per token. (proven round 2)
// ---------------------------------------------------------------------------
__global__ __launch_bounds__(256) void combine_k(
    const float* __restrict__ cur, const float* __restrict__ xW,
    const float* __restrict__ idW, const float* __restrict__ identf,
    float* __restrict__ nxt, int d)
{
    const int token = blockIdx.x;
    const int t = token & (T_ - 1);
    const int j = threadIdx.x;
    const bool hl = (t >= d);
    const float* leftp  = hl ? cur + (size_t)(token - d) * C_ : identf;
    const float* leftW  = hl ? xW  + (size_t)(token - d) * C_ : idW;
    const float* rightp = cur + (size_t)token * C_;
    const float* rightW = xW  + (size_t)token * C_;

    float q[4], k[4], v[4];
    #pragma unroll
    for (int l = 0; l < 4; ++l) {
        q[l] = leftp[l * HD + j];
        k[l] = rightp[l * HD + j];
        v[l] = leftW[l * HD + j] + rightW[l * HD + j];
    }

    __shared__ float red[4][16];
    __shared__ float att[16];
    const int lane = j & 63, wid = j >> 6;

    #pragma unroll
    for (int l = 0; l < 4; ++l)
        #pragma unroll
        for (int m = 0; m < 4; ++m) {
            float p = wave_reduce(q[l] * k[m]);
            if (lane == 0) red[wid][l * 4 + m] = p;
        }
    __syncthreads();
    if (j < 16) red[0][j] = (red[0][j] + red[1][j] + red[2][j] + red[3][j]) * 0.0625f;
    __syncthreads();
    if (j < 4) {
        float s0 = red[0][j * 4 + 0], s1 = red[0][j * 4 + 1];
        float s2 = red[0][j * 4 + 2], s3 = red[0][j * 4 + 3];
        float mx = fmaxf(fmaxf(s0, s1), fmaxf(s2, s3));
        float e0 = __expf(s0 - mx), e1 = __expf(s1 - mx);
        float e2 = __expf(s2 - mx), e3 = __expf(s3 - mx);
        float inv = 1.0f / (e0 + e1 + e2 + e3);
        att[j * 4 + 0] = e0 * inv; att[j * 4 + 1] = e1 * inv;
        att[j * 4 + 2] = e2 * inv; att[j * 4 + 3] = e3 * inv;
    }
    __syncthreads();

    float z[4];
    #pragma unroll
    for (int l = 0; l < 4; ++l)
        z[l] = att[l * 4 + 0] * v[0] + att[l * 4 + 1] * v[1]
             + att[l * 4 + 2] * v[2] + att[l * 4 + 3] * v[3];

    #pragma unroll
    for (int l = 0; l < 4; ++l) {
        float p = wave_reduce(z[l] * z[l]);
        if (lane == 0) red[wid][l] = p;
    }
    __syncthreads();
    if (j < 4) {
        float ss = red[0][j] + red[1][j] + red[2][j] + red[3][j];
        att[j] = rsqrtf(ss * (1.0f / HD) + 1e-8f);
    }
    __syncthreads();

    #pragma unroll
    for (int l = 0; l < 4; ++l) {
        float zn = z[l] * att[l] * (1.0f / (float)(l + 1));
        nxt[(size_t)token * C_ + l * HD + j] = q[l] + zn;
    }
}

// ---------------------------------------------------------------------------
extern "C" void kernel_launch(void* const* d_in, const int* in_sizes, int n_in,
                              void* d_out, int out_size, void* d_ws, size_t ws_size,
                              hipStream_t stream)
{
    const void* x     = d_in[0];
    const void* Wup   = d_in[1];
    const void* Wv    = d_in[2];
    const void* Wproj = d_in[3];
    const void* ident = d_in[4];
    const void* Wraw  = d_in[5];

    float* ws = (float*)d_ws;
    int*   flagp  = (int*)ws;                    // meta[0]
    float* sumsqp = ws + 1;                      // meta[1]
    float* W0     = ws + 256;                    // 1M
    float* W1     = W0 + (1 << 20);              // 1M
    float* G      = W1 + (1 << 20);              // 1M
    float* identf = G + (1 << 20);               // 1024
    float* idW    = identf + 1024;               // 1024
    float* stA    = idW + 1024;                  // 8M
    float* stB    = stA + (size_t)NTOK * C_;     // 8M
    float* xWb    = stB + (size_t)NTOK * C_;     // 8M

    const int NC = C_ * C_;          // 1M
    const int NX = NTOK * C_;        // 8M

    // ---- dtype detection ----
    detect_k<<<1, 256, 0, stream>>>((const u16*)Wup, flagp);

    // ---- polar(W_raw) via Newton-Schulz (f32, EXACT round-2 bit path) ----
    hipMemsetAsync(sumsqp, 0, sizeof(float), stream);
    conv_k<<<NC / 256, 256, 0, stream>>>(Wraw, W0, NC, flagp);
    sumsq_k<<<NC / 256, 256, 0, stream>>>(W0, sumsqp);
    scale_k<<<NC / 256, 256, 0, stream>>>(W0, sumsqp);

    float* X = W0; float* Y = W1;
    const dim3 gNS(16, 16);
    for (int it = 0; it < 23; ++it) {           // 18 doubling + 5 polish
        bool polish = (it >= 18);
        float a = polish ? 1.5f : 2.0f;
        float b = polish ? -0.5f : -1.0f;
        gemm_atb_f32<<<gNS, 256, 0, stream>>>(X, X, G, C_, C_, C_);
        gemm_ab_f32<<<gNS, 256, 0, stream>>>(X, G, X, Y, C_, C_, C_, a, b);
        float* tmp = X; X = Y; Y = tmp;
    }
    // X = polar(W_raw)

    conv_k<<<4, 256, 0, stream>>>(ident, identf, 1024, flagp);
    idw_k<<<4, 256, 0, stream>>>(identf, X, idW);

    // ---- q0 = x @ Wup^T  (EXACT round-2 f32 path) ----
    const dim3 g64(16, 128);
    conv_k<<<NX / 256, 256, 0, stream>>>(x, stB, NX, flagp);
    conv_k<<<NC / 256, 256, 0, stream>>>(Wup, G, NC, flagp);
    gemm_abt_f32<<<g64, 256, 0, stream>>>(stB, G, stA, NTOK, C_, C_);

    // ---- scan: 11 Hillis-Steele steps ----
    // gemm_ab_f32_big is bit-identical to round-2's gemm_ab_f32(beta=1):
    // one ascending-k fmac chain per element, only tile shape differs.
    const dim3 g128(C_ / 128, NTOK / 128);   // (8, 64)
    float* cur = stA; float* nxt = stB;
    for (int d = 1; d < T_; d <<= 1) {
        gemm_ab_f32_big<<<g128, 256, 0, stream>>>(cur, X, xWb, NTOK, C_, C_);
        combine_k<<<NTOK, 256, 0, stream>>>(cur, xWb, idW, identf, nxt, d);
        float* tmp = cur; cur = nxt; nxt = tmp;
    }
    // 11 steps (odd) -> cur == stB holds q; stA and xWb free.

    // ---- v = x @ Wv^T  (MFMA, proven output-0 path) -> xWb ----
    gemm_mfma<<<g128, 256, 0, stream>>>(x, nullptr, 2, Wv, 2, xWb, 0,
                                        flagp, NTOK, C_, C_);

    // ---- Y = (q .* v) @ Wproj^T -> d_out[0:NX]  (MFMA, proven) ----
    gemm_mfma<<<g128, 256, 0, stream>>>(cur, xWb, 0, Wproj, 2, d_out, 1,
                                        flagp, NTOK, C_, C_);

    // ---- second output: q ----
    store_k<<<NX / 256, 256, 0, stream>>>(cur, d_out, NX, (size_t)NX, flagp);
}